// Round 6
// baseline (130.162 us; speedup 1.0000x reference)
//
#include <hip/hip_runtime.h>

typedef _Float16 half8 __attribute__((ext_vector_type(8)));
typedef _Float16 half4v __attribute__((ext_vector_type(4)));
typedef __fp16 fp16x2 __attribute__((ext_vector_type(2)));
typedef float f32x4 __attribute__((ext_vector_type(4)));
typedef float float4v __attribute__((ext_vector_type(4)));

constexpr int NS = 4096;   // B*S rows
constexpr int E  = 1024;
constexpr int H  = 16;
constexpr int HD = 64;
constexpr int M  = 2048;
constexpr int HE = 1024;   // H*HD

__device__ __forceinline__ void gload16(const _Float16* g, _Float16* l) {
  __builtin_amdgcn_global_load_lds((__attribute__((address_space(1))) void*)g,
                                   (__attribute__((address_space(3))) void*)l, 16, 0, 0);
}

__device__ __forceinline__ float fexp2(float x) {
#if __has_builtin(__builtin_amdgcn_exp2f)
  return __builtin_amdgcn_exp2f(x);
#else
  return __expf(x * 0.6931471805599453f);
#endif
}

// ---------------- prep kernels ----------------

__global__ void cvt_f32_to_f16(const float* __restrict__ in, _Float16* __restrict__ out,
                               float scale) {
  int i = (blockIdx.x * 256 + threadIdx.x) * 4;
  float4v v = *(const float4v*)(in + i);
  half4v o = { (_Float16)(v[0] * scale), (_Float16)(v[1] * scale),
               (_Float16)(v[2] * scale), (_Float16)(v[3] * scale) };
  *(half4v*)(out + i) = o;
}

// in fp32 [batch][R][C] -> out fp16 [batch][C][R]
__global__ void transpose_cvt(const float* __restrict__ in, _Float16* __restrict__ out,
                              int R, int C) {
  __shared__ float tile[32][33];
  int b = blockIdx.z;
  in  += (size_t)b * R * C;
  out += (size_t)b * R * C;
  int c0 = blockIdx.x * 32, r0 = blockIdx.y * 32;
  int tx = threadIdx.x, ty = threadIdx.y;  // 32 x 8
#pragma unroll
  for (int i = 0; i < 4; ++i)
    tile[ty + 8 * i][tx] = in[(size_t)(r0 + ty + 8 * i) * C + c0 + tx];
  __syncthreads();
#pragma unroll
  for (int i = 0; i < 4; ++i)
    out[(size_t)(c0 + ty + 8 * i) * R + r0 + tx] = (_Float16)tile[tx][ty + 8 * i];
}

// two 1024x1024 transposes in one launch (z selects source)
__global__ void transpose_cvt2(const float* __restrict__ inA, const float* __restrict__ inB,
                               _Float16* __restrict__ outA, _Float16* __restrict__ outB) {
  __shared__ float tile[32][33];
  const float* in = blockIdx.z ? inB : inA;
  _Float16* out = blockIdx.z ? outB : outA;
  int c0 = blockIdx.x * 32, r0 = blockIdx.y * 32;
  int tx = threadIdx.x, ty = threadIdx.y;  // 32 x 8
#pragma unroll
  for (int i = 0; i < 4; ++i)
    tile[ty + 8 * i][tx] = in[(size_t)(r0 + ty + 8 * i) * 1024 + c0 + tx];
  __syncthreads();
#pragma unroll
  for (int i = 0; i < 4; ++i)
    out[(size_t)(c0 + ty + 8 * i) * 1024 + r0 + tx] = (_Float16)tile[tx][ty + 8 * i];
}

// ---------------- GEMM: C[M][N] = A[M][K] * Bt[N][K]^T, fp32 acc ----------------
// 128x64 tile, 8 waves (4x2), wave tile 32x32 (2x2 frags), K-step 32.
// global_load_lds dbuf, counted vmcnt, raw barriers. grid 512 -> 2 blocks/CU.

template <typename OUT_T>
__global__ __launch_bounds__(512, 4) void gemm_f16(
    const _Float16* __restrict__ A,   // [Mrows][K]
    const _Float16* __restrict__ Bt,  // [Ncols][K]
    const float* __restrict__ bias,   // [Ncols]
    OUT_T* __restrict__ C,            // [Mrows][Ncols]
    int Ncols, int K, float scale)
{
  __shared__ alignas(16) _Float16 Ab[2][8 * 512];
  __shared__ alignas(16) _Float16 Bb[2][4 * 512];
  const int tid = threadIdx.x;
  const int wave = tid >> 6, lane = tid & 63;
  const int l15 = lane & 15, l4 = lane >> 4;

  const int nwg = gridDim.x;
  int wg = (blockIdx.x & 7) * (nwg >> 3) + (blockIdx.x >> 3);  // XCD swizzle (nwg%8==0)
  const int nbn = Ncols >> 6;
  const int mblk = wg / nbn, nblk = wg % nbn;

  const _Float16* aS = A  + (size_t)(mblk * 128 + wave * 16 + l15) * K + l4 * 8;
  const _Float16* bS = Bt + (size_t)(nblk * 64 + (wave & 3) * 16 + l15) * K + l4 * 8;
  _Float16* aD0 = &Ab[0][wave * 512];
  _Float16* aD1 = &Ab[1][wave * 512];
  _Float16* bD0 = &Bb[0][(wave & 3) * 512];
  _Float16* bD1 = &Bb[1][(wave & 3) * 512];

  const int wr = wave >> 1, wc = wave & 1;  // 4x2 wave grid over 128x64
  f32x4 acc[2][2];
#pragma unroll
  for (int i = 0; i < 2; ++i)
#pragma unroll
    for (int n = 0; n < 2; ++n) acc[i][n] = (f32x4){0.f, 0.f, 0.f, 0.f};

  gload16(aS, aD0);
  if (wave < 4) gload16(bS, bD0);
  aS += 32; bS += 32;

  const int nk = K >> 5;
  for (int kt = 0; kt < nk; ++kt) {
    if (kt + 1 < nk) {
      gload16(aS, (kt & 1) ? aD0 : aD1);
      if (wave < 4) gload16(bS, (kt & 1) ? bD0 : bD1);
      aS += 32; bS += 32;
      if (wave < 4) { asm volatile("s_waitcnt vmcnt(2)" ::: "memory"); }
      else          { asm volatile("s_waitcnt vmcnt(1)" ::: "memory"); }
    } else {
      asm volatile("s_waitcnt vmcnt(0)" ::: "memory");
    }
    __builtin_amdgcn_s_barrier();
    const _Float16* Ac = (kt & 1) ? &Ab[1][0] : &Ab[0][0];
    const _Float16* Bc = (kt & 1) ? &Bb[1][0] : &Bb[0][0];
    half8 af[2], bf[2];
#pragma unroll
    for (int i = 0; i < 2; ++i) af[i] = *(const half8*)(Ac + (wr * 2 + i) * 512 + lane * 8);
#pragma unroll
    for (int n = 0; n < 2; ++n) bf[n] = *(const half8*)(Bc + (wc * 2 + n) * 512 + lane * 8);
    __builtin_amdgcn_s_setprio(1);
#pragma unroll
    for (int i = 0; i < 2; ++i)
#pragma unroll
      for (int n = 0; n < 2; ++n)
        acc[i][n] = __builtin_amdgcn_mfma_f32_16x16x32_f16(af[i], bf[n], acc[i][n], 0, 0, 0);
    __builtin_amdgcn_s_setprio(0);
    asm volatile("s_waitcnt lgkmcnt(0)" ::: "memory");
    __builtin_amdgcn_sched_barrier(0);
    __builtin_amdgcn_s_barrier();
  }

  const int row0 = mblk * 128 + wr * 32;
  const int col0 = nblk * 64 + wc * 32;
#pragma unroll
  for (int n = 0; n < 2; ++n) {
    int col = col0 + n * 16 + l15;
    float bv = bias[col];
#pragma unroll
    for (int i = 0; i < 2; ++i)
#pragma unroll
      for (int r = 0; r < 4; ++r) {
        int row = row0 + i * 16 + l4 * 4 + r;
        C[(size_t)row * Ncols + col] = (OUT_T)(acc[i][n][r] * scale + bv);
      }
  }
}

// ---------------- fused attention (M-split x2, PV lagged one tile) ----------------
// grid 1024 = 16 heads x 2 M-halves x 32 blocks of 128 q-rows; 4 waves x 32 rows.
// Iteration t: QK(t)+exp(t) overlapped with PV(t-1) whose operands (pfp, vfp)
// are in registers. V: LDS->regs within the staging iteration (no cross-iter
// LDS read -> plain double-buffer is race-free). P: single wave-local LDS buf,
// write->drain->readback in the same iteration; pipeline carries P in regs.
// LDS 40 KB (K 16 + V 16 + P 8). Unnormalized softmax, ones-column row-sums.

__global__ __launch_bounds__(256, 3) void attn_fused(
    const _Float16* __restrict__ qh,    // [NS][HE]
    const _Float16* __restrict__ Kh,    // [H][M][HD]  (pre-scaled by log2 e)
    const _Float16* __restrict__ Vth,   // [H][HD][M]
    _Float16* __restrict__ Op0,         // [NS][HE] partial sum pV, half 0
    _Float16* __restrict__ Op1,         // [NS][HE] partial sum pV, half 1
    float* __restrict__ Spart)          // [2][NS][H] partial sum p
{
  __shared__ alignas(16) _Float16 Kb[2][4096];  // 16 KB: 64m x 64k
  __shared__ alignas(16) _Float16 Vb[2][4096];  // 16 KB: 64d x 64m
  __shared__ alignas(16) _Float16 Pl[4096];     //  8 KB: 1024 halfs per wave

  int wg = (blockIdx.x & 7) * 128 + (blockIdx.x >> 3);  // 2 heads per XCD
  const int h = wg >> 6, half = (wg >> 5) & 1, sblk = wg & 31;
  const int m0 = half * 1024;
  const int tid = threadIdx.x;
  const int wave = tid >> 6, lane = tid & 63, l15 = lane & 15, l4 = lane >> 4;
  const int s0 = sblk * 128 + wave * 32;

  half8 qf[2][2];
#pragma unroll
  for (int f = 0; f < 2; ++f) {
    const _Float16* qp = qh + (size_t)(s0 + f * 16 + l15) * HE + h * HD + l4 * 8;
    qf[f][0] = *(const half8*)qp;
    qf[f][1] = *(const half8*)(qp + 32);
  }

  const _Float16* kSrc = Kh + (size_t)h * M * HD
                         + (size_t)((wave >> 1) * 16 + l15) * HD + (wave & 1) * 32 + l4 * 8;
  const _Float16* vSrc = Vth + (size_t)h * HD * M + (size_t)(wave * 16 + l15) * M + l4 * 8;
  const int dOff = wave * 512 + lane * 8;

  _Float16* Pw = &Pl[wave * 1024];
  const int pAddr = (l4 >> 1) * 128 + l15 * 8 + (l4 & 1) * 4;  // + f*512 + t*256

  half8 vones;
#pragma unroll
  for (int j = 0; j < 8; ++j) vones[j] = (_Float16)1.0f;

  f32x4 acc[2][4];
  f32x4 accs[2];
#pragma unroll
  for (int f = 0; f < 2; ++f) {
    accs[f] = (f32x4){0.f, 0.f, 0.f, 0.f};
#pragma unroll
    for (int n = 0; n < 4; ++n) acc[f][n] = (f32x4){0.f, 0.f, 0.f, 0.f};
  }

  half8 pfp[2][2];   // [half][f]  P of previous tile (A-operand frags)
  half8 vfp[2][4];   // [half][c]  V of previous tile (B-operand frags)
  f32x4 s[2][2];     // QK result of current half

#define STAGE(b, mm) {                                             \
    gload16(kSrc + (size_t)(mm) * HD,        &Kb[b][dOff]);        \
    gload16(kSrc + (size_t)((mm) + 32) * HD, &Kb[b][dOff + 2048]); \
    gload16(vSrc + (mm),                     &Vb[b][dOff]);        \
    gload16(vSrc + (mm) + 32,                &Vb[b][dOff + 2048]); }

#define QKH(b, hh) {                                                                      \
    const _Float16* Kc = &Kb[b][(hh) * 2048];                                             \
    half8 kf[4];                                                                          \
    _Pragma("unroll")                                                                     \
    for (int c = 0; c < 4; ++c) kf[c] = *(const half8*)(Kc + c * 512 + lane * 8);         \
    f32x4 z = (f32x4){0.f, 0.f, 0.f, 0.f};                                                \
    __builtin_amdgcn_s_setprio(1);                                                        \
    _Pragma("unroll")                                                                     \
    for (int f = 0; f < 2; ++f)                                                           \
      _Pragma("unroll")                                                                   \
      for (int t = 0; t < 2; ++t) {                                                       \
        s[f][t] = __builtin_amdgcn_mfma_f32_16x16x32_f16(kf[t * 2 + 0], qf[f][0], z, 0, 0, 0); \
        s[f][t] = __builtin_amdgcn_mfma_f32_16x16x32_f16(kf[t * 2 + 1], qf[f][1], s[f][t], 0, 0, 0); \
      }                                                                                   \
    __builtin_amdgcn_s_setprio(0); }

#define PVH(hh) {                                                                         \
    __builtin_amdgcn_s_setprio(1);                                                        \
    _Pragma("unroll")                                                                     \
    for (int n = 0; n < 4; ++n) {                                                         \
      acc[0][n] = __builtin_amdgcn_mfma_f32_16x16x32_f16(pfp[hh][0], vfp[hh][n], acc[0][n], 0, 0, 0); \
      acc[1][n] = __builtin_amdgcn_mfma_f32_16x16x32_f16(pfp[hh][1], vfp[hh][n], acc[1][n], 0, 0, 0); \
    }                                                                                     \
    accs[0] = __builtin_amdgcn_mfma_f32_16x16x32_f16(pfp[hh][0], vones, accs[0], 0, 0, 0); \
    accs[1] = __builtin_amdgcn_mfma_f32_16x16x32_f16(pfp[hh][1], vones, accs[1], 0, 0, 0); \
    __builtin_amdgcn_s_setprio(0); }

#define EXPW() {                                                                          \
    _Pragma("unroll")                                                                     \
    for (int f = 0; f < 2; ++f)                                                           \
      _Pragma("unroll")                                                                   \
      for (int t = 0; t < 2; ++t) {                                                       \
        fp16x2 lo = __builtin_amdgcn_cvt_pkrtz(fexp2(s[f][t][0]), fexp2(s[f][t][1]));     \
        fp16x2 hi = __builtin_amdgcn_cvt_pkrtz(fexp2(s[f][t][2]), fexp2(s[f][t][3]));     \
        *(fp16x2*)(Pw + pAddr + f * 512 + t * 256)     = lo;                              \
        *(fp16x2*)(Pw + pAddr + f * 512 + t * 256 + 2) = hi;                              \
      } }

#define RDPF(hh) {                                                                        \
    asm volatile("s_waitcnt lgkmcnt(0)" ::: "memory");                                    \
    __builtin_amdgcn_sched_barrier(0);                                                    \
    pfp[hh][0] = *(const half8*)(Pw + lane * 8);                                          \
    pfp[hh][1] = *(const half8*)(Pw + 512 + lane * 8); }

#define VREAD(b) {                                                                        \
    _Pragma("unroll")                                                                     \
    for (int hh = 0; hh < 2; ++hh)                                                        \
      _Pragma("unroll")                                                                   \
      for (int c = 0; c < 4; ++c)                                                         \
        vfp[hh][c] = *(const half8*)(&Vb[b][(hh) * 2048] + c * 512 + lane * 8); }

  STAGE(0, m0);
  for (int kt = 0; kt < 16; ++kt) {
    const int cur = kt & 1;
    if (kt < 15) {
      STAGE(cur ^ 1, m0 + (kt + 1) * 64);
      asm volatile("s_waitcnt vmcnt(4)" ::: "memory");  // this tile landed, next in flight
    } else {
      asm volatile("s_waitcnt vmcnt(0)" ::: "memory");
    }
    __builtin_amdgcn_s_barrier();   // Kb/Vb[cur] visible block-wide
    QKH(cur, 0);                    // QK of current tile, half 0
    if (kt) PVH(0);                 // PV of previous tile, half 0 (regs ready)
    EXPW();                         // exp + P write (half 0)
    RDPF(0);                        // drain; P(h0) -> regs; Pw reusable
    QKH(cur, 1);
    if (kt) PVH(1);                 // last use of vfp -> regs free
    VREAD(cur);                     // V(cur) LDS -> regs for next iteration
    EXPW();
    RDPF(1);
    __builtin_amdgcn_s_barrier();   // all waves done with Kb/Vb[cur]
  }
  PVH(0);                           // drain pipeline: PV of tile 15
  PVH(1);

  _Float16* Op = half ? Op1 : Op0;
  float* Sp = Spart + (size_t)half * (NS * H);
#pragma unroll
  for (int f = 0; f < 2; ++f) {
#pragma unroll
    for (int n = 0; n < 4; ++n)
#pragma unroll
      for (int r = 0; r < 4; ++r) {
        int row = s0 + f * 16 + l4 * 4 + r;
        Op[(size_t)row * HE + h * HD + n * 16 + l15] = (_Float16)acc[f][n][r];
      }
    if (l15 == 0) {
#pragma unroll
      for (int r = 0; r < 4; ++r) {
        int row = s0 + f * 16 + l4 * 4 + r;
        Sp[(size_t)row * H + h] = accs[f][r];
      }
    }
  }
#undef STAGE
#undef QKH
#undef PVH
#undef EXPW
#undef RDPF
#undef VREAD
}

// combine: attnh = (O0 + O1) / (S0 + S1)
__global__ void attn_combine(const _Float16* __restrict__ O0, const _Float16* __restrict__ O1,
                             const float* __restrict__ Spart, _Float16* __restrict__ out) {
  int idx = (blockIdx.x * 256 + threadIdx.x) * 8;
  int row = idx >> 10, he = idx & 1023, h = he >> 6;
  half8 a = *(const half8*)(O0 + idx);
  half8 b = *(const half8*)(O1 + idx);
  float s = Spart[(size_t)row * H + h] + Spart[(size_t)(NS + row) * H + h];
  float inv = 1.0f / s;
  half8 o;
#pragma unroll
  for (int j = 0; j < 8; ++j) o[j] = (_Float16)(((float)a[j] + (float)b[j]) * inv);
  *(half8*)(out + idx) = o;
}

// ---------------- launch ----------------

extern "C" void kernel_launch(void* const* d_in, const int* in_sizes, int n_in,
                              void* d_out, int out_size, void* d_ws, size_t ws_size,
                              hipStream_t stream) {
  const float* tensor = (const float*)d_in[0];
  const float* Wq     = (const float*)d_in[1];
  const float* bq     = (const float*)d_in[2];
  const float* Kp     = (const float*)d_in[3];
  const float* Vp     = (const float*)d_in[4];
  const float* Wd     = (const float*)d_in[5];
  const float* bd     = (const float*)d_in[6];
  float* out = (float*)d_out;

  char* ws = (char*)d_ws;
  _Float16* th    = (_Float16*)(ws);                  // [4096][1024] 8 MB; reused as Opart0
  _Float16* qhb   = (_Float16*)(ws + (8  << 20));     // 8 MB
  _Float16* attnh = (_Float16*)(ws + (16 << 20));     // 8 MB
  _Float16* Wqt   = (_Float16*)(ws + (24 << 20));     // 2 MB; reused as Spart after gemm1
  _Float16* Wdt   = (_Float16*)(ws + (26 << 20));     // 2 MB
  _Float16* Khb   = (_Float16*)(ws + (28 << 20));     // 4 MB
  _Float16* Vth   = (_Float16*)(ws + (32 << 20));     // 4 MB
  _Float16* Op0   = (_Float16*)(ws);                  // overlays th (dead after gemm1)
  _Float16* Op1   = (_Float16*)(ws + (36 << 20));     // 8 MB  (total 44 MB)
  float*    Spart = (float*)(ws + (24 << 20));        // [2][4096][16] f32, overlays Wqt

  cvt_f32_to_f16<<<(NS * E) / 1024, 256, 0, stream>>>(tensor, th, 1.0f);
  cvt_f32_to_f16<<<(H * M * HD) / 1024, 256, 0, stream>>>(Kp, Khb, 1.44269504088896f);
  transpose_cvt2<<<dim3(32, 32, 2), dim3(32, 8), 0, stream>>>(Wq, Wd, Wqt, Wdt);
  transpose_cvt<<<dim3(2, 64, 16), dim3(32, 8), 0, stream>>>(Vp, Vth, 2048, 64);

  gemm_f16<_Float16><<<512, 512, 0, stream>>>(th, Wqt, bq, qhb, HE, E, 1.0f);
  attn_fused<<<1024, 256, 0, stream>>>(qhb, Khb, Vth, Op0, Op1, Spart);
  attn_combine<<<(NS * HE) / 2048, 256, 0, stream>>>(Op0, Op1, Spart, attnh);
  gemm_f16<float><<<512, 512, 0, stream>>>(attnh, Wdt, bd, out, E, HE, 0.125f);
}

// Round 7
// 126.939 us; speedup vs baseline: 1.0254x; 1.0254x over previous
//
#include <hip/hip_runtime.h>

typedef _Float16 half8 __attribute__((ext_vector_type(8)));
typedef _Float16 half4v __attribute__((ext_vector_type(4)));
typedef __fp16 fp16x2 __attribute__((ext_vector_type(2)));
typedef float f32x4 __attribute__((ext_vector_type(4)));
typedef float f32x16 __attribute__((ext_vector_type(16)));
typedef float float4v __attribute__((ext_vector_type(4)));
typedef unsigned uint32x2 __attribute__((ext_vector_type(2)));

constexpr int NS = 4096;   // B*S rows
constexpr int E  = 1024;
constexpr int H  = 16;
constexpr int HD = 64;
constexpr int M  = 2048;
constexpr int HE = 1024;   // H*HD

__device__ __forceinline__ void gload16(const _Float16* g, _Float16* l) {
  __builtin_amdgcn_global_load_lds((__attribute__((address_space(1))) void*)g,
                                   (__attribute__((address_space(3))) void*)l, 16, 0, 0);
}

__device__ __forceinline__ float fexp2(float x) {
#if __has_builtin(__builtin_amdgcn_exp2f)
  return __builtin_amdgcn_exp2f(x);
#else
  return __expf(x * 0.6931471805599453f);
#endif
}

// pack two f32 -> one dword of 2 fp16 (RTZ)
__device__ __forceinline__ unsigned pkh(float a, float b) {
  fp16x2 t = __builtin_amdgcn_cvt_pkrtz(a, b);
  return __builtin_bit_cast(unsigned, t);
}

// lane<->lane+32 half-exchange; returns {slot_lo, slot_hi} per derivation:
// out.x = hi ? partner(b) : own(a);  out.y = hi ? own(b) : partner(a)
__device__ __forceinline__ uint32x2 pl32swap(unsigned a, unsigned b) {
#if __has_builtin(__builtin_amdgcn_permlane32_swap)
  return __builtin_amdgcn_permlane32_swap(a, b, false, false);
#else
  unsigned sa = (unsigned)__shfl_xor((int)a, 32, 64);
  unsigned sb = (unsigned)__shfl_xor((int)b, 32, 64);
  uint32x2 r;
  r.x = (threadIdx.x & 32) ? sb : a;
  r.y = (threadIdx.x & 32) ? b : sa;
  return r;
#endif
}

__device__ __forceinline__ half8 mk8(unsigned a, unsigned b, unsigned c, unsigned d) {
  union { unsigned u[4]; half8 h; } t;
  t.u[0] = a; t.u[1] = b; t.u[2] = c; t.u[3] = d;
  return t.h;
}

// ---------------- prep kernels ----------------

__global__ void cvt_f32_to_f16(const float* __restrict__ in, _Float16* __restrict__ out,
                               float scale) {
  int i = (blockIdx.x * 256 + threadIdx.x) * 4;
  float4v v = *(const float4v*)(in + i);
  half4v o = { (_Float16)(v[0] * scale), (_Float16)(v[1] * scale),
               (_Float16)(v[2] * scale), (_Float16)(v[3] * scale) };
  *(half4v*)(out + i) = o;
}

// in fp32 [batch][R][C] -> out fp16 [batch][C][R]
__global__ void transpose_cvt(const float* __restrict__ in, _Float16* __restrict__ out,
                              int R, int C) {
  __shared__ float tile[32][33];
  int b = blockIdx.z;
  in  += (size_t)b * R * C;
  out += (size_t)b * R * C;
  int c0 = blockIdx.x * 32, r0 = blockIdx.y * 32;
  int tx = threadIdx.x, ty = threadIdx.y;  // 32 x 8
#pragma unroll
  for (int i = 0; i < 4; ++i)
    tile[ty + 8 * i][tx] = in[(size_t)(r0 + ty + 8 * i) * C + c0 + tx];
  __syncthreads();
#pragma unroll
  for (int i = 0; i < 4; ++i)
    out[(size_t)(c0 + ty + 8 * i) * R + r0 + tx] = (_Float16)tile[tx][ty + 8 * i];
}

// two 1024x1024 transposes in one launch (z selects source)
__global__ void transpose_cvt2(const float* __restrict__ inA, const float* __restrict__ inB,
                               _Float16* __restrict__ outA, _Float16* __restrict__ outB) {
  __shared__ float tile[32][33];
  const float* in = blockIdx.z ? inB : inA;
  _Float16* out = blockIdx.z ? outB : outA;
  int c0 = blockIdx.x * 32, r0 = blockIdx.y * 32;
  int tx = threadIdx.x, ty = threadIdx.y;  // 32 x 8
#pragma unroll
  for (int i = 0; i < 4; ++i)
    tile[ty + 8 * i][tx] = in[(size_t)(r0 + ty + 8 * i) * 1024 + c0 + tx];
  __syncthreads();
#pragma unroll
  for (int i = 0; i < 4; ++i)
    out[(size_t)(c0 + ty + 8 * i) * 1024 + r0 + tx] = (_Float16)tile[tx][ty + 8 * i];
}

// ---------------- GEMM: C[M][N] = A[M][K] * Bt[N][K]^T, fp32 acc ----------------
// 128x64 tile, 8 waves (4x2), wave tile 32x32 (2x2 frags), K-step 32.
// global_load_lds dbuf, counted vmcnt, raw barriers. grid 512 -> 2 blocks/CU.

template <typename OUT_T>
__global__ __launch_bounds__(512, 4) void gemm_f16(
    const _Float16* __restrict__ A,   // [Mrows][K]
    const _Float16* __restrict__ Bt,  // [Ncols][K]
    const float* __restrict__ bias,   // [Ncols]
    OUT_T* __restrict__ C,            // [Mrows][Ncols]
    int Ncols, int K, float scale)
{
  __shared__ alignas(16) _Float16 Ab[2][8 * 512];
  __shared__ alignas(16) _Float16 Bb[2][4 * 512];
  const int tid = threadIdx.x;
  const int wave = tid >> 6, lane = tid & 63;
  const int l15 = lane & 15, l4 = lane >> 4;

  const int nwg = gridDim.x;
  int wg = (blockIdx.x & 7) * (nwg >> 3) + (blockIdx.x >> 3);  // XCD swizzle (nwg%8==0)
  const int nbn = Ncols >> 6;
  const int mblk = wg / nbn, nblk = wg % nbn;

  const _Float16* aS = A  + (size_t)(mblk * 128 + wave * 16 + l15) * K + l4 * 8;
  const _Float16* bS = Bt + (size_t)(nblk * 64 + (wave & 3) * 16 + l15) * K + l4 * 8;
  _Float16* aD0 = &Ab[0][wave * 512];
  _Float16* aD1 = &Ab[1][wave * 512];
  _Float16* bD0 = &Bb[0][(wave & 3) * 512];
  _Float16* bD1 = &Bb[1][(wave & 3) * 512];

  const int wr = wave >> 1, wc = wave & 1;  // 4x2 wave grid over 128x64
  f32x4 acc[2][2];
#pragma unroll
  for (int i = 0; i < 2; ++i)
#pragma unroll
    for (int n = 0; n < 2; ++n) acc[i][n] = (f32x4){0.f, 0.f, 0.f, 0.f};

  gload16(aS, aD0);
  if (wave < 4) gload16(bS, bD0);
  aS += 32; bS += 32;

  const int nk = K >> 5;
  for (int kt = 0; kt < nk; ++kt) {
    if (kt + 1 < nk) {
      gload16(aS, (kt & 1) ? aD0 : aD1);
      if (wave < 4) gload16(bS, (kt & 1) ? bD0 : bD1);
      aS += 32; bS += 32;
      if (wave < 4) { asm volatile("s_waitcnt vmcnt(2)" ::: "memory"); }
      else          { asm volatile("s_waitcnt vmcnt(1)" ::: "memory"); }
    } else {
      asm volatile("s_waitcnt vmcnt(0)" ::: "memory");
    }
    __builtin_amdgcn_s_barrier();
    const _Float16* Ac = (kt & 1) ? &Ab[1][0] : &Ab[0][0];
    const _Float16* Bc = (kt & 1) ? &Bb[1][0] : &Bb[0][0];
    half8 af[2], bf[2];
#pragma unroll
    for (int i = 0; i < 2; ++i) af[i] = *(const half8*)(Ac + (wr * 2 + i) * 512 + lane * 8);
#pragma unroll
    for (int n = 0; n < 2; ++n) bf[n] = *(const half8*)(Bc + (wc * 2 + n) * 512 + lane * 8);
    __builtin_amdgcn_s_setprio(1);
#pragma unroll
    for (int i = 0; i < 2; ++i)
#pragma unroll
      for (int n = 0; n < 2; ++n)
        acc[i][n] = __builtin_amdgcn_mfma_f32_16x16x32_f16(af[i], bf[n], acc[i][n], 0, 0, 0);
    __builtin_amdgcn_s_setprio(0);
    asm volatile("s_waitcnt lgkmcnt(0)" ::: "memory");
    __builtin_amdgcn_sched_barrier(0);
    __builtin_amdgcn_s_barrier();
  }

  const int row0 = mblk * 128 + wr * 32;
  const int col0 = nblk * 64 + wc * 32;
#pragma unroll
  for (int n = 0; n < 2; ++n) {
    int col = col0 + n * 16 + l15;
    float bv = bias[col];
#pragma unroll
    for (int i = 0; i < 2; ++i)
#pragma unroll
      for (int r = 0; r < 4; ++r) {
        int row = row0 + i * 16 + l4 * 4 + r;
        C[(size_t)row * Ncols + col] = (OUT_T)(acc[i][n][r] * scale + bv);
      }
  }
}

// ---------------- fused attention (M-split x2, 32x32 MFMA, in-register P) ----------------
// grid 1024 = 16 heads x 2 M-halves x 32 blocks of 128 q-rows; 4 waves x 32 q.
// Swapped QK with 32x32x16: lane holds S^T col q=lane&31, rows m per reg quad.
// P redistribution to the PV A-operand is a pure lane<->lane+32 exchange:
// permlane32_swap outputs ARE the A-frag dwords (no LDS round trip, no drain).
// K/V staged in LDS (global_load_lds dbuf, counted vmcnt(4)) in frag-chunk
// layout via per-lane global source addresses; all LDS reads lane-linear 16B.
// Row-sum: per-lane f32 adds + one final shfl_xor(32). Unnormalized softmax
// (K pre-scaled by log2 e). LDS 32 KB.

__global__ __launch_bounds__(256, 4) void attn_fused(
    const _Float16* __restrict__ qh,    // [NS][HE]
    const _Float16* __restrict__ Kh,    // [H][M][HD]  (pre-scaled by log2 e)
    const _Float16* __restrict__ Vth,   // [H][HD][M]
    _Float16* __restrict__ Op0,         // [NS][HE] partial sum pV, half 0
    _Float16* __restrict__ Op1,         // [NS][HE] partial sum pV, half 1
    float* __restrict__ Spart)          // [2][NS][H] partial sum p
{
  __shared__ alignas(16) _Float16 Kb[2][4096];  // 16 KB: 2 tiles x (32m x 64d)
  __shared__ alignas(16) _Float16 Vb[2][4096];  // 16 KB: 2 tiles x (64d x 32m)

  int wg = (blockIdx.x & 7) * 128 + (blockIdx.x >> 3);  // 2 heads per XCD
  const int h = wg >> 6, half = (wg >> 5) & 1, sblk = wg & 31;
  const int m0 = half * 1024;
  const int tid = threadIdx.x;
  const int wave = tid >> 6, lane = tid & 63;
  const int l31 = lane & 31, hi = lane >> 5;
  const int s0 = sblk * 128 + wave * 32;

  // Q B-frags: B[k=d][col=q]: lane holds Q[s0+l31][c*16 + hi*8 + j]
  half8 qf[4];
  {
    const _Float16* qp = qh + (size_t)(s0 + l31) * HE + h * HD + hi * 8;
    qf[0] = *(const half8*)(qp);
    qf[1] = *(const half8*)(qp + 16);
    qf[2] = *(const half8*)(qp + 32);
    qf[3] = *(const half8*)(qp + 48);
  }

  // staging: wave w stages K chunks {2w,2w+1} (same 32-m group, adjacent d16),
  // V chunks {2w,2w+1} (same d-half/tile, adjacent m16).
  const _Float16* kS = Kh + (size_t)h * M * HD
                       + (size_t)((wave >> 1) * 32 + l31) * HD + (wave & 1) * 32 + hi * 8;
  const _Float16* vS = Vth + (size_t)(h * HD + (wave & 1) * 32 + l31) * M
                       + (wave >> 1) * 32 + hi * 8;
  const int dOff = wave * 1024 + lane * 8;

  f32x16 accA = {0.f,0.f,0.f,0.f,0.f,0.f,0.f,0.f,0.f,0.f,0.f,0.f,0.f,0.f,0.f,0.f};
  f32x16 accB = {0.f,0.f,0.f,0.f,0.f,0.f,0.f,0.f,0.f,0.f,0.f,0.f,0.f,0.f,0.f,0.f};
  float lsum = 0.f;

#define STAGE(b, mm) {                                        \
    gload16(kS + (size_t)(mm) * HD,      &Kb[b][dOff]);       \
    gload16(kS + (size_t)(mm) * HD + 16, &Kb[b][dOff + 512]); \
    gload16(vS + (mm),                   &Vb[b][dOff]);       \
    gload16(vS + (mm) + 16,              &Vb[b][dOff + 512]); }

  STAGE(0, m0);
  for (int kt = 0; kt < 16; ++kt) {
    const int cur = kt & 1;
    if (kt < 15) {
      STAGE(cur ^ 1, m0 + (kt + 1) * 64);
      asm volatile("s_waitcnt vmcnt(4)" ::: "memory");  // this tile landed, next in flight
    } else {
      asm volatile("s_waitcnt vmcnt(0)" ::: "memory");
    }
    __builtin_amdgcn_s_barrier();

#pragma unroll
    for (int mt = 0; mt < 2; ++mt) {
      const _Float16* Kc = &Kb[cur][mt * 2048];
      const _Float16* Vc = &Vb[cur][mt * 2048];
      // QK: A=K[m][d], 4 d-quarters
      half8 kf0 = *(const half8*)(Kc + lane * 8);
      half8 kf1 = *(const half8*)(Kc + 512 + lane * 8);
      half8 kf2 = *(const half8*)(Kc + 1024 + lane * 8);
      half8 kf3 = *(const half8*)(Kc + 1536 + lane * 8);
      f32x16 s = {0.f,0.f,0.f,0.f,0.f,0.f,0.f,0.f,0.f,0.f,0.f,0.f,0.f,0.f,0.f,0.f};
      __builtin_amdgcn_s_setprio(1);
      s = __builtin_amdgcn_mfma_f32_32x32x16_f16(kf0, qf[0], s, 0, 0, 0);
      s = __builtin_amdgcn_mfma_f32_32x32x16_f16(kf1, qf[1], s, 0, 0, 0);
      s = __builtin_amdgcn_mfma_f32_32x32x16_f16(kf2, qf[2], s, 0, 0, 0);
      s = __builtin_amdgcn_mfma_f32_32x32x16_f16(kf3, qf[3], s, 0, 0, 0);
      __builtin_amdgcn_s_setprio(0);
      // exp + pack: pd[qd*2+c] holds m = qd*8 + 2c + {0,1} + 4*hi
      unsigned pd[8];
      float la = 0.f;
#pragma unroll
      for (int i = 0; i < 8; ++i) {
        float a = fexp2(s[2 * i]);
        float b = fexp2(s[2 * i + 1]);
        la += a + b;
        pd[i] = pkh(a, b);
      }
      lsum += la;
      // lane+-32 exchange -> PV A-frags (m 0..15 and 16..31 of this tile)
      uint32x2 w0 = pl32swap(pd[0], pd[2]);
      uint32x2 w1 = pl32swap(pd[1], pd[3]);
      uint32x2 w2 = pl32swap(pd[4], pd[6]);
      uint32x2 w3 = pl32swap(pd[5], pd[7]);
      half8 pa0 = mk8(w0.x, w1.x, w0.y, w1.y);
      half8 pa1 = mk8(w2.x, w3.x, w2.y, w3.y);
      // V B-frags: chunk (dt, mc) at offset (dt*2+mc)*512
      half8 v00 = *(const half8*)(Vc + lane * 8);
      half8 v01 = *(const half8*)(Vc + 512 + lane * 8);
      half8 v10 = *(const half8*)(Vc + 1024 + lane * 8);
      half8 v11 = *(const half8*)(Vc + 1536 + lane * 8);
      __builtin_amdgcn_s_setprio(1);
      accA = __builtin_amdgcn_mfma_f32_32x32x16_f16(pa0, v00, accA, 0, 0, 0);
      accA = __builtin_amdgcn_mfma_f32_32x32x16_f16(pa1, v01, accA, 0, 0, 0);
      accB = __builtin_amdgcn_mfma_f32_32x32x16_f16(pa0, v10, accB, 0, 0, 0);
      accB = __builtin_amdgcn_mfma_f32_32x32x16_f16(pa1, v11, accB, 0, 0, 0);
      __builtin_amdgcn_s_setprio(0);
    }
    asm volatile("s_waitcnt lgkmcnt(0)" ::: "memory");  // all buf[cur] reads retired
    __builtin_amdgcn_s_barrier();
  }
#undef STAGE

  _Float16* Op = half ? Op1 : Op0;
  float* Sp = Spart + (size_t)half * (NS * H);
#pragma unroll
  for (int r = 0; r < 16; ++r) {
    int q = s0 + (r & 3) + 8 * (r >> 2) + 4 * hi;
    Op[(size_t)q * HE + h * HD + l31]      = (_Float16)accA[r];
    Op[(size_t)q * HE + h * HD + 32 + l31] = (_Float16)accB[r];
  }
  float tot = lsum + __shfl_xor(lsum, 32, 64);
  if (hi == 0) Sp[(size_t)(s0 + l31) * H + h] = tot;
}

// combine: attnh = (O0 + O1) / (S0 + S1)
__global__ void attn_combine(const _Float16* __restrict__ O0, const _Float16* __restrict__ O1,
                             const float* __restrict__ Spart, _Float16* __restrict__ out) {
  int idx = (blockIdx.x * 256 + threadIdx.x) * 8;
  int row = idx >> 10, he = idx & 1023, h = he >> 6;
  half8 a = *(const half8*)(O0 + idx);
  half8 b = *(const half8*)(O1 + idx);
  float s = Spart[(size_t)row * H + h] + Spart[(size_t)(NS + row) * H + h];
  float inv = 1.0f / s;
  half8 o;
#pragma unroll
  for (int j = 0; j < 8; ++j) o[j] = (_Float16)(((float)a[j] + (float)b[j]) * inv);
  *(half8*)(out + idx) = o;
}

// ---------------- launch ----------------

extern "C" void kernel_launch(void* const* d_in, const int* in_sizes, int n_in,
                              void* d_out, int out_size, void* d_ws, size_t ws_size,
                              hipStream_t stream) {
  const float* tensor = (const float*)d_in[0];
  const float* Wq     = (const float*)d_in[1];
  const float* bq     = (const float*)d_in[2];
  const float* Kp     = (const float*)d_in[3];
  const float* Vp     = (const float*)d_in[4];
  const float* Wd     = (const float*)d_in[5];
  const float* bd     = (const float*)d_in[6];
  float* out = (float*)d_out;

  char* ws = (char*)d_ws;
  _Float16* th    = (_Float16*)(ws);                  // [4096][1024] 8 MB; reused as Opart0
  _Float16* qhb   = (_Float16*)(ws + (8  << 20));     // 8 MB
  _Float16* attnh = (_Float16*)(ws + (16 << 20));     // 8 MB
  _Float16* Wqt   = (_Float16*)(ws + (24 << 20));     // 2 MB; reused as Spart after gemm1
  _Float16* Wdt   = (_Float16*)(ws + (26 << 20));     // 2 MB
  _Float16* Khb   = (_Float16*)(ws + (28 << 20));     // 4 MB
  _Float16* Vth   = (_Float16*)(ws + (32 << 20));     // 4 MB
  _Float16* Op0   = (_Float16*)(ws);                  // overlays th (dead after gemm1)
  _Float16* Op1   = (_Float16*)(ws + (36 << 20));     // 8 MB  (total 44 MB)
  float*    Spart = (float*)(ws + (24 << 20));        // [2][4096][16] f32, overlays Wqt

  cvt_f32_to_f16<<<(NS * E) / 1024, 256, 0, stream>>>(tensor, th, 1.0f);
  cvt_f32_to_f16<<<(H * M * HD) / 1024, 256, 0, stream>>>(Kp, Khb, 1.44269504088896f);
  transpose_cvt2<<<dim3(32, 32, 2), dim3(32, 8), 0, stream>>>(Wq, Wd, Wqt, Wdt);
  transpose_cvt<<<dim3(2, 64, 16), dim3(32, 8), 0, stream>>>(Vp, Vth, 2048, 64);

  gemm_f16<_Float16><<<512, 512, 0, stream>>>(th, Wqt, bq, qhb, HE, E, 1.0f);
  attn_fused<<<1024, 256, 0, stream>>>(qhb, Khb, Vth, Op0, Op1, Spart);
  attn_combine<<<(NS * HE) / 2048, 256, 0, stream>>>(Op0, Op1, Spart, attnh);
  gemm_f16<float><<<512, 512, 0, stream>>>(attnh, Wdt, bd, out, E, HE, 0.125f);
}

// Round 8
// 124.330 us; speedup vs baseline: 1.0469x; 1.0210x over previous
//
#include <hip/hip_runtime.h>

typedef _Float16 half8 __attribute__((ext_vector_type(8)));
typedef _Float16 half4v __attribute__((ext_vector_type(4)));
typedef __fp16 fp16x2 __attribute__((ext_vector_type(2)));
typedef float f32x4 __attribute__((ext_vector_type(4)));
typedef float f32x16 __attribute__((ext_vector_type(16)));
typedef float float4v __attribute__((ext_vector_type(4)));
typedef unsigned uint32x2 __attribute__((ext_vector_type(2)));

constexpr int NS = 4096;   // B*S rows
constexpr int E  = 1024;
constexpr int H  = 16;
constexpr int HD = 64;
constexpr int M  = 2048;
constexpr int HE = 1024;   // H*HD

__device__ __forceinline__ void gload16(const _Float16* g, _Float16* l) {
  __builtin_amdgcn_global_load_lds((__attribute__((address_space(1))) void*)g,
                                   (__attribute__((address_space(3))) void*)l, 16, 0, 0);
}

__device__ __forceinline__ float fexp2(float x) {
#if __has_builtin(__builtin_amdgcn_exp2f)
  return __builtin_amdgcn_exp2f(x);
#else
  return __expf(x * 0.6931471805599453f);
#endif
}

// pack two f32 -> one dword of 2 fp16 (RTZ)
__device__ __forceinline__ unsigned pkh(float a, float b) {
  fp16x2 t = __builtin_amdgcn_cvt_pkrtz(a, b);
  return __builtin_bit_cast(unsigned, t);
}

// lane<->lane+32 half-exchange
__device__ __forceinline__ uint32x2 pl32swap(unsigned a, unsigned b) {
#if __has_builtin(__builtin_amdgcn_permlane32_swap)
  return __builtin_amdgcn_permlane32_swap(a, b, false, false);
#else
  unsigned sa = (unsigned)__shfl_xor((int)a, 32, 64);
  unsigned sb = (unsigned)__shfl_xor((int)b, 32, 64);
  uint32x2 r;
  r.x = (threadIdx.x & 32) ? sb : a;
  r.y = (threadIdx.x & 32) ? b : sa;
  return r;
#endif
}

__device__ __forceinline__ half8 mk8(unsigned a, unsigned b, unsigned c, unsigned d) {
  union { unsigned u[4]; half8 h; } t;
  t.u[0] = a; t.u[1] = b; t.u[2] = c; t.u[3] = d;
  return t.h;
}

// ---------------- prep kernels ----------------

__global__ void cvt_f32_to_f16(const float* __restrict__ in, _Float16* __restrict__ out,
                               float scale) {
  int i = (blockIdx.x * 256 + threadIdx.x) * 4;
  float4v v = *(const float4v*)(in + i);
  half4v o = { (_Float16)(v[0] * scale), (_Float16)(v[1] * scale),
               (_Float16)(v[2] * scale), (_Float16)(v[3] * scale) };
  *(half4v*)(out + i) = o;
}

// in fp32 [batch][R][C] -> out fp16 [batch][C][R]
__global__ void transpose_cvt(const float* __restrict__ in, _Float16* __restrict__ out,
                              int R, int C) {
  __shared__ float tile[32][33];
  int b = blockIdx.z;
  in  += (size_t)b * R * C;
  out += (size_t)b * R * C;
  int c0 = blockIdx.x * 32, r0 = blockIdx.y * 32;
  int tx = threadIdx.x, ty = threadIdx.y;  // 32 x 8
#pragma unroll
  for (int i = 0; i < 4; ++i)
    tile[ty + 8 * i][tx] = in[(size_t)(r0 + ty + 8 * i) * C + c0 + tx];
  __syncthreads();
#pragma unroll
  for (int i = 0; i < 4; ++i)
    out[(size_t)(c0 + ty + 8 * i) * R + r0 + tx] = (_Float16)tile[tx][ty + 8 * i];
}

// two 1024x1024 transposes in one launch (z selects source)
__global__ void transpose_cvt2(const float* __restrict__ inA, const float* __restrict__ inB,
                               _Float16* __restrict__ outA, _Float16* __restrict__ outB) {
  __shared__ float tile[32][33];
  const float* in = blockIdx.z ? inB : inA;
  _Float16* out = blockIdx.z ? outB : outA;
  int c0 = blockIdx.x * 32, r0 = blockIdx.y * 32;
  int tx = threadIdx.x, ty = threadIdx.y;  // 32 x 8
#pragma unroll
  for (int i = 0; i < 4; ++i)
    tile[ty + 8 * i][tx] = in[(size_t)(r0 + ty + 8 * i) * 1024 + c0 + tx];
  __syncthreads();
#pragma unroll
  for (int i = 0; i < 4; ++i)
    out[(size_t)(c0 + ty + 8 * i) * 1024 + r0 + tx] = (_Float16)tile[tx][ty + 8 * i];
}

// ---------------- GEMM: C[M][N] = A[M][K] * Bt[N][K]^T, fp32 acc ----------------
// 128x64 tile, 8 waves (4x2), wave tile 32x32 (2x2 frags), K-step 32.
// SINGLE __syncthreads per K-step: sync (drains own tile-t loads, issued a
// full phase earlier) -> issue stage(t+1) -> compute(t). All ds_reads are
// consumed by MFMAs before the next sync, so no trailing drain is needed.

template <typename OUT_T>
__global__ __launch_bounds__(512, 4) void gemm_f16(
    const _Float16* __restrict__ A,   // [Mrows][K]
    const _Float16* __restrict__ Bt,  // [Ncols][K]
    const float* __restrict__ bias,   // [Ncols]
    OUT_T* __restrict__ C,            // [Mrows][Ncols]
    int Ncols, int K, float scale)
{
  __shared__ alignas(16) _Float16 Ab[2][8 * 512];
  __shared__ alignas(16) _Float16 Bb[2][4 * 512];
  const int tid = threadIdx.x;
  const int wave = tid >> 6, lane = tid & 63;
  const int l15 = lane & 15, l4 = lane >> 4;

  const int nwg = gridDim.x;
  int wg = (blockIdx.x & 7) * (nwg >> 3) + (blockIdx.x >> 3);  // XCD swizzle (nwg%8==0)
  const int nbn = Ncols >> 6;
  const int mblk = wg / nbn, nblk = wg % nbn;

  const _Float16* aS = A  + (size_t)(mblk * 128 + wave * 16 + l15) * K + l4 * 8;
  const _Float16* bS = Bt + (size_t)(nblk * 64 + (wave & 3) * 16 + l15) * K + l4 * 8;
  _Float16* aD0 = &Ab[0][wave * 512];
  _Float16* aD1 = &Ab[1][wave * 512];
  _Float16* bD0 = &Bb[0][(wave & 3) * 512];
  _Float16* bD1 = &Bb[1][(wave & 3) * 512];

  const int wr = wave >> 1, wc = wave & 1;  // 4x2 wave grid over 128x64
  f32x4 acc[2][2];
#pragma unroll
  for (int i = 0; i < 2; ++i)
#pragma unroll
    for (int n = 0; n < 2; ++n) acc[i][n] = (f32x4){0.f, 0.f, 0.f, 0.f};

  gload16(aS, aD0);
  if (wave < 4) gload16(bS, bD0);
  aS += 32; bS += 32;

  const int nk = K >> 5;
  for (int kt = 0; kt < nk; ++kt) {
    __syncthreads();   // own tile-kt loads drained + all waves' loads visible
    if (kt + 1 < nk) {
      gload16(aS, (kt & 1) ? aD0 : aD1);
      if (wave < 4) gload16(bS, (kt & 1) ? bD0 : bD1);
      aS += 32; bS += 32;
    }
    const _Float16* Ac = (kt & 1) ? &Ab[1][0] : &Ab[0][0];
    const _Float16* Bc = (kt & 1) ? &Bb[1][0] : &Bb[0][0];
    half8 af[2], bf[2];
#pragma unroll
    for (int i = 0; i < 2; ++i) af[i] = *(const half8*)(Ac + (wr * 2 + i) * 512 + lane * 8);
#pragma unroll
    for (int n = 0; n < 2; ++n) bf[n] = *(const half8*)(Bc + (wc * 2 + n) * 512 + lane * 8);
    __builtin_amdgcn_s_setprio(1);
#pragma unroll
    for (int i = 0; i < 2; ++i)
#pragma unroll
      for (int n = 0; n < 2; ++n)
        acc[i][n] = __builtin_amdgcn_mfma_f32_16x16x32_f16(af[i], bf[n], acc[i][n], 0, 0, 0);
    __builtin_amdgcn_s_setprio(0);
  }

  const int row0 = mblk * 128 + wr * 32;
  const int col0 = nblk * 64 + wc * 32;
#pragma unroll
  for (int n = 0; n < 2; ++n) {
    int col = col0 + n * 16 + l15;
    float bv = bias[col];
#pragma unroll
    for (int i = 0; i < 2; ++i)
#pragma unroll
      for (int r = 0; r < 4; ++r) {
        int row = row0 + i * 16 + l4 * 4 + r;
        C[(size_t)row * Ncols + col] = (OUT_T)(acc[i][n][r] * scale + bv);
      }
  }
}

// ---------------- fused attention (M-split x2, 32x32 MFMA, in-register P) ----------------
// grid 1024 = 16 heads x 2 M-halves x 32 blocks of 128 q-rows; 4 waves x 32 q.
// SINGLE __syncthreads per 64-m tile (see gemm comment). Two independent QK
// chains (the two 32-m subtiles) issue back-to-back for MFMA ILP; fused
// exp/pack/permlane for both; PV in two 4-MFMA groups with late V reads.
// Unnormalized softmax (K pre-scaled by log2 e), row-sum in VALU + final
// shfl_xor(32). LDS 32 KB, all LDS accesses lane-linear 16B (0 conflicts).

__global__ __launch_bounds__(256, 4) void attn_fused(
    const _Float16* __restrict__ qh,    // [NS][HE]
    const _Float16* __restrict__ Kh,    // [H][M][HD]  (pre-scaled by log2 e)
    const _Float16* __restrict__ Vth,   // [H][HD][M]
    _Float16* __restrict__ Op0,         // [NS][HE] partial sum pV, half 0
    _Float16* __restrict__ Op1,         // [NS][HE] partial sum pV, half 1
    float* __restrict__ Spart)          // [2][NS][H] partial sum p
{
  __shared__ alignas(16) _Float16 Kb[2][4096];  // 16 KB: 2 subtiles x (32m x 64d)
  __shared__ alignas(16) _Float16 Vb[2][4096];  // 16 KB: 2 subtiles x (64d x 32m)

  int wg = (blockIdx.x & 7) * 128 + (blockIdx.x >> 3);  // 2 heads per XCD
  const int h = wg >> 6, half = (wg >> 5) & 1, sblk = wg & 31;
  const int m0 = half * 1024;
  const int tid = threadIdx.x;
  const int wave = tid >> 6, lane = tid & 63;
  const int l31 = lane & 31, hi = lane >> 5;
  const int s0 = sblk * 128 + wave * 32;

  // Q B-frags: lane holds Q[s0+l31][c*16 + hi*8 + j]
  half8 qf[4];
  {
    const _Float16* qp = qh + (size_t)(s0 + l31) * HE + h * HD + hi * 8;
    qf[0] = *(const half8*)(qp);
    qf[1] = *(const half8*)(qp + 16);
    qf[2] = *(const half8*)(qp + 32);
    qf[3] = *(const half8*)(qp + 48);
  }

  const _Float16* kS = Kh + (size_t)h * M * HD
                       + (size_t)((wave >> 1) * 32 + l31) * HD + (wave & 1) * 32 + hi * 8;
  const _Float16* vS = Vth + (size_t)(h * HD + (wave & 1) * 32 + l31) * M
                       + (wave >> 1) * 32 + hi * 8;
  const int dOff = wave * 1024 + lane * 8;

  f32x16 accA = {0.f,0.f,0.f,0.f,0.f,0.f,0.f,0.f,0.f,0.f,0.f,0.f,0.f,0.f,0.f,0.f};
  f32x16 accB = {0.f,0.f,0.f,0.f,0.f,0.f,0.f,0.f,0.f,0.f,0.f,0.f,0.f,0.f,0.f,0.f};
  float lsum = 0.f;

#define STAGE(b, mm) {                                        \
    gload16(kS + (size_t)(mm) * HD,      &Kb[b][dOff]);       \
    gload16(kS + (size_t)(mm) * HD + 16, &Kb[b][dOff + 512]); \
    gload16(vS + (mm),                   &Vb[b][dOff]);       \
    gload16(vS + (mm) + 16,              &Vb[b][dOff + 512]); }

  STAGE(0, m0);
  for (int kt = 0; kt < 16; ++kt) {
    const int cur = kt & 1;
    __syncthreads();   // own tile-kt loads drained + all waves' loads visible
    if (kt < 15) STAGE(cur ^ 1, m0 + (kt + 1) * 64);

    const _Float16* Kc = &Kb[cur][0];
    const _Float16* Vc = &Vb[cur][0];
    half8 kf[8];
#pragma unroll
    for (int c = 0; c < 8; ++c) kf[c] = *(const half8*)(Kc + c * 512 + lane * 8);
    f32x16 sA = {0.f,0.f,0.f,0.f,0.f,0.f,0.f,0.f,0.f,0.f,0.f,0.f,0.f,0.f,0.f,0.f};
    f32x16 sB = sA;
    __builtin_amdgcn_s_setprio(1);
#pragma unroll
    for (int c = 0; c < 4; ++c)
      sA = __builtin_amdgcn_mfma_f32_32x32x16_f16(kf[c], qf[c], sA, 0, 0, 0);
#pragma unroll
    for (int c = 0; c < 4; ++c)
      sB = __builtin_amdgcn_mfma_f32_32x32x16_f16(kf[4 + c], qf[c], sB, 0, 0, 0);
    __builtin_amdgcn_s_setprio(0);

    // exp + pack for both subtiles
    unsigned pdA[8], pdB[8];
    float la = 0.f;
#pragma unroll
    for (int i = 0; i < 8; ++i) {
      float a0 = fexp2(sA[2 * i]);
      float a1 = fexp2(sA[2 * i + 1]);
      float b0 = fexp2(sB[2 * i]);
      float b1 = fexp2(sB[2 * i + 1]);
      la += (a0 + a1) + (b0 + b1);
      pdA[i] = pkh(a0, a1);
      pdB[i] = pkh(b0, b1);
    }
    lsum += la;
    uint32x2 wA0 = pl32swap(pdA[0], pdA[2]);
    uint32x2 wA1 = pl32swap(pdA[1], pdA[3]);
    uint32x2 wA2 = pl32swap(pdA[4], pdA[6]);
    uint32x2 wA3 = pl32swap(pdA[5], pdA[7]);
    half8 paA0 = mk8(wA0.x, wA1.x, wA0.y, wA1.y);
    half8 paA1 = mk8(wA2.x, wA3.x, wA2.y, wA3.y);
    uint32x2 wB0 = pl32swap(pdB[0], pdB[2]);
    uint32x2 wB1 = pl32swap(pdB[1], pdB[3]);
    uint32x2 wB2 = pl32swap(pdB[4], pdB[6]);
    uint32x2 wB3 = pl32swap(pdB[5], pdB[7]);
    half8 paB0 = mk8(wB0.x, wB1.x, wB0.y, wB1.y);
    half8 paB1 = mk8(wB2.x, wB3.x, wB2.y, wB3.y);

    // PV subtile 0 (V chunks 0..3), then subtile 1 (chunks 4..7)
    {
      half8 v0 = *(const half8*)(Vc + lane * 8);
      half8 v1 = *(const half8*)(Vc + 512 + lane * 8);
      half8 v2 = *(const half8*)(Vc + 1024 + lane * 8);
      half8 v3 = *(const half8*)(Vc + 1536 + lane * 8);
      __builtin_amdgcn_s_setprio(1);
      accA = __builtin_amdgcn_mfma_f32_32x32x16_f16(paA0, v0, accA, 0, 0, 0);
      accA = __builtin_amdgcn_mfma_f32_32x32x16_f16(paA1, v1, accA, 0, 0, 0);
      accB = __builtin_amdgcn_mfma_f32_32x32x16_f16(paA0, v2, accB, 0, 0, 0);
      accB = __builtin_amdgcn_mfma_f32_32x32x16_f16(paA1, v3, accB, 0, 0, 0);
      __builtin_amdgcn_s_setprio(0);
    }
    {
      half8 v0 = *(const half8*)(Vc + 2048 + lane * 8);
      half8 v1 = *(const half8*)(Vc + 2560 + lane * 8);
      half8 v2 = *(const half8*)(Vc + 3072 + lane * 8);
      half8 v3 = *(const half8*)(Vc + 3584 + lane * 8);
      __builtin_amdgcn_s_setprio(1);
      accA = __builtin_amdgcn_mfma_f32_32x32x16_f16(paB0, v0, accA, 0, 0, 0);
      accA = __builtin_amdgcn_mfma_f32_32x32x16_f16(paB1, v1, accA, 0, 0, 0);
      accB = __builtin_amdgcn_mfma_f32_32x32x16_f16(paB0, v2, accB, 0, 0, 0);
      accB = __builtin_amdgcn_mfma_f32_32x32x16_f16(paB1, v3, accB, 0, 0, 0);
      __builtin_amdgcn_s_setprio(0);
    }
  }
#undef STAGE

  _Float16* Op = half ? Op1 : Op0;
  float* Sp = Spart + (size_t)half * (NS * H);
#pragma unroll
  for (int r = 0; r < 16; ++r) {
    int q = s0 + (r & 3) + 8 * (r >> 2) + 4 * hi;
    Op[(size_t)q * HE + h * HD + l31]      = (_Float16)accA[r];
    Op[(size_t)q * HE + h * HD + 32 + l31] = (_Float16)accB[r];
  }
  float tot = lsum + __shfl_xor(lsum, 32, 64);
  if (hi == 0) Sp[(size_t)(s0 + l31) * H + h] = tot;
}

// combine: attnh = (O0 + O1) / (S0 + S1)
__global__ void attn_combine(const _Float16* __restrict__ O0, const _Float16* __restrict__ O1,
                             const float* __restrict__ Spart, _Float16* __restrict__ out) {
  int idx = (blockIdx.x * 256 + threadIdx.x) * 8;
  int row = idx >> 10, he = idx & 1023, h = he >> 6;
  half8 a = *(const half8*)(O0 + idx);
  half8 b = *(const half8*)(O1 + idx);
  float s = Spart[(size_t)row * H + h] + Spart[(size_t)(NS + row) * H + h];
  float inv = 1.0f / s;
  half8 o;
#pragma unroll
  for (int j = 0; j < 8; ++j) o[j] = (_Float16)(((float)a[j] + (float)b[j]) * inv);
  *(half8*)(out + idx) = o;
}

// ---------------- launch ----------------

extern "C" void kernel_launch(void* const* d_in, const int* in_sizes, int n_in,
                              void* d_out, int out_size, void* d_ws, size_t ws_size,
                              hipStream_t stream) {
  const float* tensor = (const float*)d_in[0];
  const float* Wq     = (const float*)d_in[1];
  const float* bq     = (const float*)d_in[2];
  const float* Kp     = (const float*)d_in[3];
  const float* Vp     = (const float*)d_in[4];
  const float* Wd     = (const float*)d_in[5];
  const float* bd     = (const float*)d_in[6];
  float* out = (float*)d_out;

  char* ws = (char*)d_ws;
  _Float16* th    = (_Float16*)(ws);                  // [4096][1024] 8 MB; reused as Opart0
  _Float16* qhb   = (_Float16*)(ws + (8  << 20));     // 8 MB
  _Float16* attnh = (_Float16*)(ws + (16 << 20));     // 8 MB
  _Float16* Wqt   = (_Float16*)(ws + (24 << 20));     // 2 MB; reused as Spart after gemm1
  _Float16* Wdt   = (_Float16*)(ws + (26 << 20));     // 2 MB
  _Float16* Khb   = (_Float16*)(ws + (28 << 20));     // 4 MB
  _Float16* Vth   = (_Float16*)(ws + (32 << 20));     // 4 MB
  _Float16* Op0   = (_Float16*)(ws);                  // overlays th (dead after gemm1)
  _Float16* Op1   = (_Float16*)(ws + (36 << 20));     // 8 MB  (total 44 MB)
  float*    Spart = (float*)(ws + (24 << 20));        // [2][4096][16] f32, overlays Wqt

  cvt_f32_to_f16<<<(NS * E) / 1024, 256, 0, stream>>>(tensor, th, 1.0f);
  cvt_f32_to_f16<<<(H * M * HD) / 1024, 256, 0, stream>>>(Kp, Khb, 1.44269504088896f);
  transpose_cvt2<<<dim3(32, 32, 2), dim3(32, 8), 0, stream>>>(Wq, Wd, Wqt, Wdt);
  transpose_cvt<<<dim3(2, 64, 16), dim3(32, 8), 0, stream>>>(Vp, Vth, 2048, 64);

  gemm_f16<_Float16><<<512, 512, 0, stream>>>(th, Wqt, bq, qhb, HE, E, 1.0f);
  attn_fused<<<1024, 256, 0, stream>>>(qhb, Khb, Vth, Op0, Op1, Spart);
  attn_combine<<<(NS * HE) / 2048, 256, 0, stream>>>(Op0, Op1, Spart, attnh);
  gemm_f16<float><<<512, 512, 0, stream>>>(attnh, Wdt, bd, out, E, HE, 0.125f);
}